// Round 1
// baseline (3258.427 us; speedup 1.0000x reference)
//
#include <hip/hip_runtime.h>
#include <hip/hip_bf16.h>
#include <cstddef>

// Problem constants
#define BATCH 4
#define INC   256
#define HID   16
#define NL    9
#define HH    192
#define WW    192
#define PIX   (HH*WW)          // 36864
#define OUTC  128
#define CATC  (NL*HID*2)       // 288

// ---------------------------------------------------------------------------
// Kernel A: h0 = 1x1 conv(cen)+b0, h1 = 3x3 conv(cen)+b1  (both 256->16, SAME)
// One block = 16x16 pixel tile for one batch. Channels staged in LDS in chunks
// of 16 with a +/-1 halo. Weights are wave-uniform -> scalar-cache loads.
// ---------------------------------------------------------------------------
__global__ __launch_bounds__(256) void kernelA(
    const float* __restrict__ cen, const float* __restrict__ w0,
    const float* __restrict__ b0,  const float* __restrict__ w1,
    const float* __restrict__ b1,  float* __restrict__ h0,
    float* __restrict__ h1) {
  __shared__ float lds[16 * 18 * 18];
  const int lx = threadIdx.x, ly = threadIdx.y;
  const int tid = ly * 16 + lx;
  const int x0 = blockIdx.x * 16, y0 = blockIdx.y * 16, b = blockIdx.z;

  float acc0[16], acc1[16];
#pragma unroll
  for (int d = 0; d < 16; ++d) { acc0[d] = 0.f; acc1[d] = 0.f; }

  for (int cb = 0; cb < INC; cb += 16) {
    __syncthreads();  // protect LDS reuse from previous chunk's readers
    for (int i = tid; i < 16 * 18 * 18; i += 256) {
      int c = i / 324; int rem = i - c * 324;
      int yy = rem / 18; int xx = rem - yy * 18;
      int gy = y0 + yy - 1, gx = x0 + xx - 1;
      float v = 0.f;
      if (gy >= 0 && gy < HH && gx >= 0 && gx < WW)
        v = cen[(((size_t)b * INC + cb + c) * HH + gy) * WW + gx];
      lds[i] = v;
    }
    __syncthreads();
    for (int c = 0; c < 16; ++c) {
      float v[9];
#pragma unroll
      for (int r = 0; r < 9; ++r) {
        const int dy = r / 3, dx = r - (r / 3) * 3;
        v[r] = lds[(c * 18 + ly + dy) * 18 + lx + dx];
      }
      const int cc = cb + c;
#pragma unroll
      for (int d = 0; d < 16; ++d)
        acc0[d] = fmaf(w0[d * INC + cc], v[4], acc0[d]);
#pragma unroll
      for (int d = 0; d < 16; ++d) {
        float a = acc1[d];
#pragma unroll
        for (int r = 0; r < 9; ++r)
          a = fmaf(w1[(d * INC + cc) * 9 + r], v[r], a);
        acc1[d] = a;
      }
    }
  }
  const int y = y0 + ly, x = x0 + lx;
#pragma unroll
  for (int d = 0; d < 16; ++d) {
    const size_t o = (((size_t)b * HID + d) * HH + y) * WW + x;
    h0[o] = acc0[d] + b0[d];
    h1[o] = acc1[d] + b1[d];
  }
}

// ---------------------------------------------------------------------------
// Kernel B: per-pixel grouped matvecs + 9x9 attention + this branch's half of
// the final 1x1 conv (128 x 144). Thread = pixel. ACCUM=false writes
// bias + W0*outv0 to d_out; the second launch accumulates.
// ---------------------------------------------------------------------------
template <int SHIFT, int BRANCH, bool ACCUM>
__global__ __launch_bounds__(64) void kernelB(
    const float* __restrict__ h,   const float* __restrict__ w1,
    const float* __restrict__ w2,  const float* __restrict__ w3,
    const float* __restrict__ scale, const float* __restrict__ out_w,
    const float* __restrict__ out_b, float* __restrict__ out) {
  const int pix = blockIdx.x * 64 + threadIdx.x;
  const int b = pix / PIX; const int rem = pix - b * PIX;
  const int y = rem / WW;  const int x = rem - y * WW;
  const float sc = scale[BRANCH];

  // shift offsets for groups 0..7 (group 8 = center, +h)
  constexpr int DY[9] = {-1, -1, -1, 0, 1, 1, 1, 0, 0};
  constexpr int DX[9] = {-1, 0, 1, 1, 1, 0, -1, -1, 0};

  const float* __restrict__ hb = h + (size_t)b * HID * PIX;

  auto loadX = [&](int g, float* xv) {
    if (g == 8) {
#pragma unroll
      for (int c = 0; c < 16; ++c) xv[c] = hb[c * PIX + y * WW + x];
    } else {
      const int yy = y + DY[g] * SHIFT, xx = x + DX[g] * SHIFT;
      if (yy >= 0 && yy < HH && xx >= 0 && xx < WW) {
#pragma unroll
        for (int c = 0; c < 16; ++c) xv[c] = -hb[c * PIX + yy * WW + xx];
      } else {
#pragma unroll
        for (int c = 0; c < 16; ++c) xv[c] = 0.f;
      }
    }
  };

  // Phase A: o1[q] for all groups
  float o1[9][16];
#pragma unroll
  for (int q = 0; q < 9; ++q) {
    float xq[16];
    loadX(q, xq);
#pragma unroll
    for (int d = 0; d < 16; ++d) {
      float a0 = 0.f, a1 = 0.f;
#pragma unroll
      for (int c = 0; c < 16; c += 2) {
        a0 = fmaf(w1[(q * 16 + d) * 16 + c],     xq[c],     a0);
        a1 = fmaf(w1[(q * 16 + d) * 16 + c + 1], xq[c + 1], a1);
      }
      o1[q][d] = a0 + a1;
    }
  }

  // Phase B: o2[p], logits row, softmax over q
  float attn[9][9];
#pragma unroll
  for (int p = 0; p < 9; ++p) {
    float xp[16];
    loadX(p, xp);
    float o2p[16];
#pragma unroll
    for (int d = 0; d < 16; ++d) {
      float a0 = 0.f, a1 = 0.f;
#pragma unroll
      for (int c = 0; c < 16; c += 2) {
        a0 = fmaf(w2[(p * 16 + d) * 16 + c],     xp[c],     a0);
        a1 = fmaf(w2[(p * 16 + d) * 16 + c + 1], xp[c + 1], a1);
      }
      o2p[d] = a0 + a1;
    }
    float lg[9];
#pragma unroll
    for (int q = 0; q < 9; ++q) {
      float a0 = 0.f, a1 = 0.f;
#pragma unroll
      for (int d = 0; d < 16; d += 2) {
        a0 = fmaf(o2p[d],     o1[q][d],     a0);
        a1 = fmaf(o2p[d + 1], o1[q][d + 1], a1);
      }
      lg[q] = sc * (a0 + a1);
    }
    float m = lg[0];
#pragma unroll
    for (int q = 1; q < 9; ++q) m = fmaxf(m, lg[q]);
    float s = 0.f;
#pragma unroll
    for (int q = 0; q < 9; ++q) { lg[q] = __expf(lg[q] - m); s += lg[q]; }
    const float inv = 1.0f / s;
#pragma unroll
    for (int q = 0; q < 9; ++q) attn[p][q] = lg[q] * inv;
  }

  // Phase C: outv[p][:] = sum_q attn[p][q] * o3[q][:]
  float ov[144];
#pragma unroll
  for (int i = 0; i < 144; ++i) ov[i] = 0.f;
#pragma unroll
  for (int q = 0; q < 9; ++q) {
    float xq[16];
    loadX(q, xq);
    float o3q[16];
#pragma unroll
    for (int d = 0; d < 16; ++d) {
      float a0 = 0.f, a1 = 0.f;
#pragma unroll
      for (int c = 0; c < 16; c += 2) {
        a0 = fmaf(w3[(q * 16 + d) * 16 + c],     xq[c],     a0);
        a1 = fmaf(w3[(q * 16 + d) * 16 + c + 1], xq[c + 1], a1);
      }
      o3q[d] = a0 + a1;
    }
#pragma unroll
    for (int p = 0; p < 9; ++p) {
      const float a = attn[p][q];
#pragma unroll
      for (int d = 0; d < 16; ++d)
        ov[p * 16 + d] = fmaf(a, o3q[d], ov[p * 16 + d]);
    }
  }

  // Phase D: this branch's half of the final conv (128 x 144)
  const size_t obase = (size_t)b * OUTC * PIX + (size_t)y * WW + x;
  for (int o = 0; o < OUTC; ++o) {
    const float* __restrict__ wr = out_w + (size_t)o * CATC + BRANCH * 144;
    float a0 = 0.f, a1 = 0.f, a2 = 0.f, a3 = 0.f;
#pragma unroll
    for (int i = 0; i < 144; i += 4) {
      a0 = fmaf(wr[i],     ov[i],     a0);
      a1 = fmaf(wr[i + 1], ov[i + 1], a1);
      a2 = fmaf(wr[i + 2], ov[i + 2], a2);
      a3 = fmaf(wr[i + 3], ov[i + 3], a3);
    }
    float r = (a0 + a1) + (a2 + a3);
    const size_t oo = obase + (size_t)o * PIX;
    if (ACCUM) r += out[oo]; else r += out_b[o];
    out[oo] = r;
  }
}

// ---------------------------------------------------------------------------
extern "C" void kernel_launch(void* const* d_in, const int* in_sizes, int n_in,
                              void* d_out, int out_size, void* d_ws, size_t ws_size,
                              hipStream_t stream) {
  const float* cen   = (const float*)d_in[0];
  const float* in_w0 = (const float*)d_in[1];
  const float* in_b0 = (const float*)d_in[2];
  const float* in_w1 = (const float*)d_in[3];
  const float* in_b1 = (const float*)d_in[4];
  const float* w1_0  = (const float*)d_in[5];
  const float* w2_0  = (const float*)d_in[6];
  const float* w3_0  = (const float*)d_in[7];
  const float* w1_1  = (const float*)d_in[8];
  const float* w2_1  = (const float*)d_in[9];
  const float* w3_1  = (const float*)d_in[10];
  const float* scale = (const float*)d_in[11];
  const float* out_w = (const float*)d_in[12];
  const float* out_b = (const float*)d_in[13];
  float* out = (float*)d_out;

  float* h0 = (float*)d_ws;                          // 4*16*192*192 floats
  float* h1 = h0 + (size_t)BATCH * HID * PIX;        // same size

  dim3 gA(WW / 16, HH / 16, BATCH), bA(16, 16);
  hipLaunchKernelGGL(kernelA, gA, bA, 0, stream,
                     cen, in_w0, in_b0, in_w1, in_b1, h0, h1);

  const int nb = (BATCH * PIX) / 64;  // 2304 blocks
  hipLaunchKernelGGL((kernelB<1, 0, false>), dim3(nb), dim3(64), 0, stream,
                     h0, w1_0, w2_0, w3_0, scale, out_w, out_b, out);
  hipLaunchKernelGGL((kernelB<5, 1, true>), dim3(nb), dim3(64), 0, stream,
                     h1, w1_1, w2_1, w3_1, scale, out_w, out_b, out);
}

// Round 2
// 2714.516 us; speedup vs baseline: 1.2004x; 1.2004x over previous
//
#include <hip/hip_runtime.h>
#include <hip/hip_bf16.h>
#include <cstddef>
#include <cstdint>

// Problem constants
#define BATCH 4
#define INC   256
#define HID   16
#define NL    9
#define HH    192
#define WW    192
#define PIX   (HH*WW)          // 36864
#define BPIX  (BATCH*PIX)      // 147456
#define OUTC  128
#define CATC  (NL*HID*2)       // 288
#define CATK  160              // per-branch K padded 144 -> 160 (5 x 32)

typedef __attribute__((ext_vector_type(8))) short bf16x8;
typedef __attribute__((ext_vector_type(4))) float f32x4;

__device__ inline unsigned short f2bf(float f) {
  unsigned int u = __float_as_uint(f);
  u += 0x7FFF + ((u >> 16) & 1);   // round-to-nearest-even
  return (unsigned short)(u >> 16);
}

// ---------------------------------------------------------------------------
// Kernel A (unchanged from round 1): h0 = 1x1 conv + b0, h1 = 3x3 conv + b1
// ---------------------------------------------------------------------------
__global__ __launch_bounds__(256) void kernelA(
    const float* __restrict__ cen, const float* __restrict__ w0,
    const float* __restrict__ b0,  const float* __restrict__ w1,
    const float* __restrict__ b1,  float* __restrict__ h0,
    float* __restrict__ h1) {
  __shared__ float lds[16 * 18 * 18];
  const int lx = threadIdx.x, ly = threadIdx.y;
  const int tid = ly * 16 + lx;
  const int x0 = blockIdx.x * 16, y0 = blockIdx.y * 16, b = blockIdx.z;

  float acc0[16], acc1[16];
#pragma unroll
  for (int d = 0; d < 16; ++d) { acc0[d] = 0.f; acc1[d] = 0.f; }

  for (int cb = 0; cb < INC; cb += 16) {
    __syncthreads();
    for (int i = tid; i < 16 * 18 * 18; i += 256) {
      int c = i / 324; int rem = i - c * 324;
      int yy = rem / 18; int xx = rem - yy * 18;
      int gy = y0 + yy - 1, gx = x0 + xx - 1;
      float v = 0.f;
      if (gy >= 0 && gy < HH && gx >= 0 && gx < WW)
        v = cen[(((size_t)b * INC + cb + c) * HH + gy) * WW + gx];
      lds[i] = v;
    }
    __syncthreads();
    for (int c = 0; c < 16; ++c) {
      float v[9];
#pragma unroll
      for (int r = 0; r < 9; ++r) {
        const int dy = r / 3, dx = r - (r / 3) * 3;
        v[r] = lds[(c * 18 + ly + dy) * 18 + lx + dx];
      }
      const int cc = cb + c;
#pragma unroll
      for (int d = 0; d < 16; ++d)
        acc0[d] = fmaf(w0[d * INC + cc], v[4], acc0[d]);
#pragma unroll
      for (int d = 0; d < 16; ++d) {
        float a = acc1[d];
#pragma unroll
        for (int r = 0; r < 9; ++r)
          a = fmaf(w1[(d * INC + cc) * 9 + r], v[r], a);
        acc1[d] = a;
      }
    }
  }
  const int y = y0 + ly, x = x0 + lx;
#pragma unroll
  for (int d = 0; d < 16; ++d) {
    const size_t o = (((size_t)b * HID + d) * HH + y) * WW + x;
    h0[o] = acc0[d] + b0[d];
    h1[o] = acc1[d] + b1[d];
  }
}

// ---------------------------------------------------------------------------
// wprep: out_w (fp32, [128][288]) -> wb (bf16, [branch][128][CATK]), K-padded
// ---------------------------------------------------------------------------
__global__ __launch_bounds__(256) void wprep(const float* __restrict__ out_w,
                                             unsigned short* __restrict__ wb) {
  int idx = blockIdx.x * 256 + threadIdx.x;
  if (idx >= 2 * OUTC * CATK) return;
  int k = idx % CATK; int rest = idx / CATK;
  int o = rest % OUTC; int br = rest / OUTC;
  float v = (k < 144) ? out_w[o * CATC + br * 144 + k] : 0.f;
  wb[idx] = f2bf(v);
}

// ---------------------------------------------------------------------------
// Kernel B1: per-pixel attention (phases A-C), d-dimension split in halves to
// keep registers < 256 (no spills). Writes ov as bf16 cat rows [pix][CATK].
// ---------------------------------------------------------------------------
template <int SHIFT, int BRANCH>
__global__ __launch_bounds__(64, 2) void kernelB1(
    const float* __restrict__ h,  const float* __restrict__ w1,
    const float* __restrict__ w2, const float* __restrict__ w3,
    const float* __restrict__ scale, unsigned short* __restrict__ cat) {
  const int pix = blockIdx.x * 64 + threadIdx.x;   // global bpix
  const int b = pix / PIX; const int rem = pix - b * PIX;
  const int y = rem / WW;  const int x = rem - y * WW;
  const float sc = scale[BRANCH];

  constexpr int DY[9] = {-1, -1, -1, 0, 1, 1, 1, 0, 0};
  constexpr int DX[9] = {-1, 0, 1, 1, 1, 0, -1, -1, 0};

  const float* __restrict__ hb = h + (size_t)b * HID * PIX;

  auto loadX = [&](int g, float* xv) {
    if (g == 8) {
#pragma unroll
      for (int c = 0; c < 16; ++c) xv[c] = hb[c * PIX + y * WW + x];
    } else {
      const int yy = y + DY[g] * SHIFT, xx = x + DX[g] * SHIFT;
      if (yy >= 0 && yy < HH && xx >= 0 && xx < WW) {
#pragma unroll
        for (int c = 0; c < 16; ++c) xv[c] = -hb[c * PIX + yy * WW + xx];
      } else {
#pragma unroll
        for (int c = 0; c < 16; ++c) xv[c] = 0.f;
      }
    }
  };

  // ---- Phase A/B: logits[p][q] = sum_d o2[p,d]*o1[q,d], d in two halves ----
  float logits[81];
#pragma unroll
  for (int i = 0; i < 81; ++i) logits[i] = 0.f;

#pragma unroll
  for (int half = 0; half < 2; ++half) {
    float o1h[72];
#pragma unroll
    for (int q = 0; q < 9; ++q) {
      float xq[16];
      loadX(q, xq);
#pragma unroll
      for (int dd = 0; dd < 8; ++dd) {
        const int d = half * 8 + dd;
        float a0 = 0.f, a1 = 0.f;
#pragma unroll
        for (int c = 0; c < 16; c += 2) {
          a0 = fmaf(w1[(q * 16 + d) * 16 + c],     xq[c],     a0);
          a1 = fmaf(w1[(q * 16 + d) * 16 + c + 1], xq[c + 1], a1);
        }
        o1h[q * 8 + dd] = a0 + a1;
      }
    }
#pragma unroll
    for (int p = 0; p < 9; ++p) {
      float xp[16];
      loadX(p, xp);
      float o2h[8];
#pragma unroll
      for (int dd = 0; dd < 8; ++dd) {
        const int d = half * 8 + dd;
        float a0 = 0.f, a1 = 0.f;
#pragma unroll
        for (int c = 0; c < 16; c += 2) {
          a0 = fmaf(w2[(p * 16 + d) * 16 + c],     xp[c],     a0);
          a1 = fmaf(w2[(p * 16 + d) * 16 + c + 1], xp[c + 1], a1);
        }
        o2h[dd] = a0 + a1;
      }
#pragma unroll
      for (int q = 0; q < 9; ++q) {
        float a0 = 0.f, a1 = 0.f;
#pragma unroll
        for (int dd = 0; dd < 8; dd += 2) {
          a0 = fmaf(o2h[dd],     o1h[q * 8 + dd],     a0);
          a1 = fmaf(o2h[dd + 1], o1h[q * 8 + dd + 1], a1);
        }
        logits[p * 9 + q] += a0 + a1;
      }
    }
  }

  // ---- softmax over q (per p), scale applied once ----
  float attn[81];
#pragma unroll
  for (int p = 0; p < 9; ++p) {
    float lg[9];
#pragma unroll
    for (int q = 0; q < 9; ++q) lg[q] = sc * logits[p * 9 + q];
    float m = lg[0];
#pragma unroll
    for (int q = 1; q < 9; ++q) m = fmaxf(m, lg[q]);
    float s = 0.f;
#pragma unroll
    for (int q = 0; q < 9; ++q) { lg[q] = __expf(lg[q] - m); s += lg[q]; }
    const float inv = 1.0f / s;
#pragma unroll
    for (int q = 0; q < 9; ++q) attn[p * 9 + q] = lg[q] * inv;
  }

  // ---- Phase C: ov[p][d] = sum_q attn[p][q]*o3[q][d], halves; store bf16 ----
  uint4* __restrict__ catrow = (uint4*)(cat + (size_t)pix * CATK);
#pragma unroll
  for (int half = 0; half < 2; ++half) {
    float ovh[72];
#pragma unroll
    for (int i = 0; i < 72; ++i) ovh[i] = 0.f;
#pragma unroll
    for (int q = 0; q < 9; ++q) {
      float xq[16];
      loadX(q, xq);
      float o3h[8];
#pragma unroll
      for (int dd = 0; dd < 8; ++dd) {
        const int d = half * 8 + dd;
        float a0 = 0.f, a1 = 0.f;
#pragma unroll
        for (int c = 0; c < 16; c += 2) {
          a0 = fmaf(w3[(q * 16 + d) * 16 + c],     xq[c],     a0);
          a1 = fmaf(w3[(q * 16 + d) * 16 + c + 1], xq[c + 1], a1);
        }
        o3h[dd] = a0 + a1;
      }
#pragma unroll
      for (int p = 0; p < 9; ++p) {
        const float a = attn[p * 9 + q];
#pragma unroll
        for (int dd = 0; dd < 8; ++dd)
          ovh[p * 8 + dd] = fmaf(a, o3h[dd], ovh[p * 8 + dd]);
      }
    }
    // store: 8 bf16 per p at k = p*16 + half*8  -> uint4 index 2p + half
#pragma unroll
    for (int p = 0; p < 9; ++p) {
      uint4 w;
      w.x = (unsigned)f2bf(ovh[p * 8 + 0]) | ((unsigned)f2bf(ovh[p * 8 + 1]) << 16);
      w.y = (unsigned)f2bf(ovh[p * 8 + 2]) | ((unsigned)f2bf(ovh[p * 8 + 3]) << 16);
      w.z = (unsigned)f2bf(ovh[p * 8 + 4]) | ((unsigned)f2bf(ovh[p * 8 + 5]) << 16);
      w.w = (unsigned)f2bf(ovh[p * 8 + 6]) | ((unsigned)f2bf(ovh[p * 8 + 7]) << 16);
      catrow[p * 2 + half] = w;
    }
  }
  // zero K-pad [144,160)
  catrow[18] = make_uint4(0, 0, 0, 0);
  catrow[19] = make_uint4(0, 0, 0, 0);
}

// ---------------------------------------------------------------------------
// Kernel B2: final conv half as bf16 MFMA GEMM. out[o][bpix] (+)= wb @ cat.
// Wave = one 16-pixel tile x all 128 outputs (8 m-tiles), K = 160 (5 chunks).
// ---------------------------------------------------------------------------
template <int BRANCH, bool ACCUM>
__global__ __launch_bounds__(256) void kernelB2(
    const unsigned short* __restrict__ cat, const unsigned short* __restrict__ wb,
    const float* __restrict__ out_b, float* __restrict__ out) {
  const int wave = threadIdx.x >> 6;
  const int lane = threadIdx.x & 63;
  const int tile = blockIdx.x * 4 + wave;        // 0 .. BPIX/16-1
  const int bpix0 = tile * 16;
  const int n = lane & 15, quad = lane >> 4;

  const bf16x8* __restrict__ bp =
      (const bf16x8*)(cat + (size_t)(bpix0 + n) * CATK + quad * 8);
  const unsigned short* __restrict__ wrow0 =
      wb + ((size_t)BRANCH * OUTC + n) * CATK + quad * 8;

  f32x4 acc[8];
#pragma unroll
  for (int mt = 0; mt < 8; ++mt) acc[mt] = (f32x4){0.f, 0.f, 0.f, 0.f};

#pragma unroll
  for (int kc = 0; kc < 5; ++kc) {
    const bf16x8 bfrag = bp[kc * 4];   // +kc*32 bf16
#pragma unroll
    for (int mt = 0; mt < 8; ++mt) {
      const bf16x8 afrag =
          *(const bf16x8*)(wrow0 + (size_t)mt * 16 * CATK + kc * 32);
      acc[mt] = __builtin_amdgcn_mfma_f32_16x16x32_bf16(afrag, bfrag, acc[mt], 0, 0, 0);
    }
  }

  const int b = bpix0 / PIX;
  const int pin = bpix0 - b * PIX + n;
#pragma unroll
  for (int mt = 0; mt < 8; ++mt) {
#pragma unroll
    for (int i = 0; i < 4; ++i) {
      const int o = mt * 16 + quad * 4 + i;
      const size_t addr = ((size_t)(b * OUTC + o)) * PIX + pin;
      float r = acc[mt][i];
      if (ACCUM) r += out[addr]; else r += out_b[o];
      out[addr] = r;
    }
  }
}

// ---------------------------------------------------------------------------
extern "C" void kernel_launch(void* const* d_in, const int* in_sizes, int n_in,
                              void* d_out, int out_size, void* d_ws, size_t ws_size,
                              hipStream_t stream) {
  const float* cen   = (const float*)d_in[0];
  const float* in_w0 = (const float*)d_in[1];
  const float* in_b0 = (const float*)d_in[2];
  const float* in_w1 = (const float*)d_in[3];
  const float* in_b1 = (const float*)d_in[4];
  const float* w1_0  = (const float*)d_in[5];
  const float* w2_0  = (const float*)d_in[6];
  const float* w3_0  = (const float*)d_in[7];
  const float* w1_1  = (const float*)d_in[8];
  const float* w2_1  = (const float*)d_in[9];
  const float* w3_1  = (const float*)d_in[10];
  const float* scale = (const float*)d_in[11];
  const float* out_w = (const float*)d_in[12];
  const float* out_b = (const float*)d_in[13];
  float* out = (float*)d_out;

  // ws layout
  float* h0 = (float*)d_ws;                              // 2,359,296 f32
  float* h1 = h0 + (size_t)BATCH * HID * PIX;            // 2,359,296 f32
  unsigned short* cat = (unsigned short*)(h1 + (size_t)BATCH * HID * PIX); // BPIX*CATK bf16 = 47.2MB
  unsigned short* wb  = cat + (size_t)BPIX * CATK;       // 2*128*160 bf16

  dim3 gA(WW / 16, HH / 16, BATCH), bA(16, 16);
  hipLaunchKernelGGL(kernelA, gA, bA, 0, stream,
                     cen, in_w0, in_b0, in_w1, in_b1, h0, h1);

  hipLaunchKernelGGL(wprep, dim3((2 * OUTC * CATK + 255) / 256), dim3(256), 0, stream,
                     out_w, wb);

  const int nb1 = BPIX / 64;        // 2304
  const int nb2 = (BPIX / 16) / 4;  // 2304

  hipLaunchKernelGGL((kernelB1<1, 0>), dim3(nb1), dim3(64), 0, stream,
                     h0, w1_0, w2_0, w3_0, scale, cat);
  hipLaunchKernelGGL((kernelB2<0, false>), dim3(nb2), dim3(256), 0, stream,
                     cat, wb, out_b, out);

  hipLaunchKernelGGL((kernelB1<5, 1>), dim3(nb1), dim3(64), 0, stream,
                     h1, w1_1, w2_1, w3_1, scale, cat);
  hipLaunchKernelGGL((kernelB2<1, true>), dim3(nb2), dim3(256), 0, stream,
                     cat, wb, out_b, out);
}

// Round 3
// 2669.221 us; speedup vs baseline: 1.2207x; 1.0170x over previous
//
#include <hip/hip_runtime.h>
#include <hip/hip_bf16.h>
#include <cstddef>
#include <cstdint>

// Problem constants
#define BATCH 4
#define INC   256
#define HID   16
#define NL    9
#define HH    192
#define WW    192
#define PIX   (HH*WW)          // 36864
#define BPIX  (BATCH*PIX)      // 147456
#define OUTC  128
#define CATC  (NL*HID*2)       // 288
#define CATK  160              // per-branch K padded 144 -> 160 (5 x 32)

typedef __attribute__((ext_vector_type(8))) short bf16x8;
typedef __attribute__((ext_vector_type(4))) float f32x4;
typedef unsigned short ushort_t;

__device__ inline unsigned short f2bf(float f) {
  unsigned int u = __float_as_uint(f);
  u += 0x7FFF + ((u >> 16) & 1);   // round-to-nearest-even
  return (unsigned short)(u >> 16);
}
__device__ inline float bf2f(unsigned short s) {
  return __uint_as_float(((unsigned)s) << 16);
}
__device__ inline unsigned pack2(float a, float b) {
  return (unsigned)f2bf(a) | ((unsigned)f2bf(b) << 16);
}

// ---------------------------------------------------------------------------
// kernelP: cen (NCHW fp32) -> cen_t hi/lo (NHWC bf16 planes)
// block = (x-tile 16, y, b); LDS transpose for coalescing both sides.
// ---------------------------------------------------------------------------
__global__ __launch_bounds__(256) void kernelP(const float* __restrict__ cen,
                                               ushort_t* __restrict__ th,
                                               ushort_t* __restrict__ tl) {
  __shared__ float t[256][17];
  const int b = blockIdx.z, y = blockIdx.y, x0 = blockIdx.x * 16;
  const int tid = threadIdx.x;
#pragma unroll
  for (int k = 0; k < 16; ++k) {
    int i = tid + k * 256; int c = i >> 4, xl = i & 15;
    t[c][xl] = cen[((size_t)(b * 256 + c)) * PIX + (size_t)y * WW + x0 + xl];
  }
  __syncthreads();
  const size_t obase = (((size_t)b * HH + y) * WW + x0) * 256;
#pragma unroll
  for (int xl = 0; xl < 16; ++xl) {
    float v = t[tid][xl];
    unsigned short hi = f2bf(v);
    th[obase + (size_t)xl * 256 + tid] = hi;
    tl[obase + (size_t)xl * 256 + tid] = f2bf(v - bf2f(hi));
  }
}

// ---------------------------------------------------------------------------
// wprepA: build MFMA-frag-ready bf16 hi/lo weights for the two input convs.
// wA1[s][kc][lane][j] = w1[d=lane&15][c=kc*32+(lane>>4)*8+j][shift s]
// wA0[kc][lane][j]    = w0[d=lane&15][c=...]
// ---------------------------------------------------------------------------
__global__ __launch_bounds__(256) void wprepA(
    const float* __restrict__ w0, const float* __restrict__ w1,
    ushort_t* __restrict__ wA0hi, ushort_t* __restrict__ wA0lo,
    ushort_t* __restrict__ wA1hi, ushort_t* __restrict__ wA1lo) {
  int idx = blockIdx.x * 256 + threadIdx.x;
  if (idx < 36864) {
    int j = idx & 7, l = (idx >> 3) & 63, kc = (idx >> 9) & 7, s = idx >> 12;
    int d = l & 15, c = kc * 32 + (l >> 4) * 8 + j;
    float v = w1[(size_t)(d * 256 + c) * 9 + s];
    unsigned short hi = f2bf(v);
    wA1hi[idx] = hi; wA1lo[idx] = f2bf(v - bf2f(hi));
  }
  if (idx < 4096) {
    int j = idx & 7, l = (idx >> 3) & 63, kc = idx >> 9;
    int d = l & 15, c = kc * 32 + (l >> 4) * 8 + j;
    float v = w0[d * 256 + c];
    unsigned short hi = f2bf(v);
    wA0hi[idx] = hi; wA0lo[idx] = f2bf(v - bf2f(hi));
  }
}

// ---------------------------------------------------------------------------
// wprepB: out_w (fp32, [128][288]) -> wb (bf16, [branch][128][CATK]), K-padded
// ---------------------------------------------------------------------------
__global__ __launch_bounds__(256) void wprepB(const float* __restrict__ out_w,
                                              ushort_t* __restrict__ wb) {
  int idx = blockIdx.x * 256 + threadIdx.x;
  if (idx >= 2 * OUTC * CATK) return;
  int k = idx % CATK; int rest = idx / CATK;
  int o = rest % OUTC; int br = rest / OUTC;
  float v = (k < 144) ? out_w[o * CATC + br * 144 + k] : 0.f;
  wb[idx] = f2bf(v);
}

// ---------------------------------------------------------------------------
// kernelA_mfma inner tile: acc1 += 3x3 conv (9 shifts), acc0 += 1x1 (center).
// 3 passes per chunk: hi*w_hi + lo*w_hi + hi*w_lo  (fp32-grade precision).
// ---------------------------------------------------------------------------
template <bool SAFE>
__device__ inline void a_tile(const ushort_t* __restrict__ th,
                              const ushort_t* __restrict__ tl,
                              const ushort_t* __restrict__ wA0hi,
                              const ushort_t* __restrict__ wA0lo,
                              const ushort_t* __restrict__ wA1hi,
                              const ushort_t* __restrict__ wA1lo,
                              int b, int y, int px, f32x4& acc0, f32x4& acc1) {
  const int lane = threadIdx.x & 63;
  const int quad = lane >> 4;
  const bf16x8 bz = {0, 0, 0, 0, 0, 0, 0, 0};
#pragma unroll
  for (int sy = 0; sy < 3; ++sy) {
    const int yy = y + sy - 1;
    const bool yok = SAFE || ((unsigned)yy < (unsigned)HH);
#pragma unroll
    for (int sx = 0; sx < 3; ++sx) {
      const int xx = px + sx - 1;
      const bool ok = SAFE || (yok && ((unsigned)xx < (unsigned)WW));
      const int cy = SAFE ? yy : (ok ? yy : 0);
      const int cx = SAFE ? xx : (ok ? xx : 0);
      const size_t base = (((size_t)(b * HH + cy) * WW) + cx) * 256 + quad * 8;
      const int s = sy * 3 + sx;
      const ushort_t* wh = wA1hi + s * 4096 + lane * 8;
      const ushort_t* wl = wA1lo + s * 4096 + lane * 8;
#pragma unroll
      for (int kc = 0; kc < 8; ++kc) {
        bf16x8 bhi = *(const bf16x8*)(th + base + kc * 32);
        bf16x8 blo = *(const bf16x8*)(tl + base + kc * 32);
        if (!SAFE && !ok) { bhi = bz; blo = bz; }
        bf16x8 ahi = *(const bf16x8*)(wh + kc * 512);
        bf16x8 alo = *(const bf16x8*)(wl + kc * 512);
        acc1 = __builtin_amdgcn_mfma_f32_16x16x32_bf16(ahi, bhi, acc1, 0, 0, 0);
        acc1 = __builtin_amdgcn_mfma_f32_16x16x32_bf16(ahi, blo, acc1, 0, 0, 0);
        acc1 = __builtin_amdgcn_mfma_f32_16x16x32_bf16(alo, bhi, acc1, 0, 0, 0);
        if (s == 4) {
          bf16x8 a0h = *(const bf16x8*)(wA0hi + kc * 512 + lane * 8);
          bf16x8 a0l = *(const bf16x8*)(wA0lo + kc * 512 + lane * 8);
          acc0 = __builtin_amdgcn_mfma_f32_16x16x32_bf16(a0h, bhi, acc0, 0, 0, 0);
          acc0 = __builtin_amdgcn_mfma_f32_16x16x32_bf16(a0h, blo, acc0, 0, 0, 0);
          acc0 = __builtin_amdgcn_mfma_f32_16x16x32_bf16(a0l, bhi, acc0, 0, 0, 0);
        }
      }
    }
  }
}

__global__ __launch_bounds__(256) void kernelA_mfma(
    const ushort_t* __restrict__ th, const ushort_t* __restrict__ tl,
    const ushort_t* __restrict__ wA0hi, const ushort_t* __restrict__ wA0lo,
    const ushort_t* __restrict__ wA1hi, const ushort_t* __restrict__ wA1lo,
    const float* __restrict__ b0, const float* __restrict__ b1,
    float* __restrict__ h0, float* __restrict__ h1) {
  const int lane = threadIdx.x & 63, wave = threadIdx.x >> 6;
  const int n = lane & 15, quad = lane >> 4;
  const int y = blockIdx.y, b = blockIdx.z;
  const int wpx0 = blockIdx.x * 64 + wave * 16;
  const int px = wpx0 + n;
  f32x4 acc0 = {0.f, 0.f, 0.f, 0.f}, acc1 = {0.f, 0.f, 0.f, 0.f};

  const bool safe = (y >= 1) && (y <= HH - 2) && (wpx0 >= 1) && (wpx0 + 16 <= WW - 1);
  if (safe)
    a_tile<true>(th, tl, wA0hi, wA0lo, wA1hi, wA1lo, b, y, px, acc0, acc1);
  else
    a_tile<false>(th, tl, wA0hi, wA0lo, wA1hi, wA1lo, b, y, px, acc0, acc1);

  const size_t prow = (size_t)y * WW + px;
#pragma unroll
  for (int i = 0; i < 4; ++i) {
    const int d = quad * 4 + i;
    h0[((size_t)(b * HID + d)) * PIX + prow] = acc0[i] + b0[d];
    h1[((size_t)(b * HID + d)) * PIX + prow] = acc1[i] + b1[d];
  }
}

// ---------------------------------------------------------------------------
// kernelA_f32: fallback (round-2 version) when ws too small for cen_t planes.
// ---------------------------------------------------------------------------
__global__ __launch_bounds__(256) void kernelA_f32(
    const float* __restrict__ cen, const float* __restrict__ w0,
    const float* __restrict__ b0,  const float* __restrict__ w1,
    const float* __restrict__ b1,  float* __restrict__ h0,
    float* __restrict__ h1) {
  __shared__ float lds[16 * 18 * 18];
  const int lx = threadIdx.x, ly = threadIdx.y;
  const int tid = ly * 16 + lx;
  const int x0 = blockIdx.x * 16, y0 = blockIdx.y * 16, b = blockIdx.z;

  float acc0[16], acc1[16];
#pragma unroll
  for (int d = 0; d < 16; ++d) { acc0[d] = 0.f; acc1[d] = 0.f; }

  for (int cb = 0; cb < INC; cb += 16) {
    __syncthreads();
    for (int i = tid; i < 16 * 18 * 18; i += 256) {
      int c = i / 324; int rem = i - c * 324;
      int yy = rem / 18; int xx = rem - yy * 18;
      int gy = y0 + yy - 1, gx = x0 + xx - 1;
      float v = 0.f;
      if (gy >= 0 && gy < HH && gx >= 0 && gx < WW)
        v = cen[(((size_t)b * INC + cb + c) * HH + gy) * WW + gx];
      lds[i] = v;
    }
    __syncthreads();
    for (int c = 0; c < 16; ++c) {
      float v[9];
#pragma unroll
      for (int r = 0; r < 9; ++r) {
        const int dy = r / 3, dx = r - (r / 3) * 3;
        v[r] = lds[(c * 18 + ly + dy) * 18 + lx + dx];
      }
      const int cc = cb + c;
#pragma unroll
      for (int d = 0; d < 16; ++d)
        acc0[d] = fmaf(w0[d * INC + cc], v[4], acc0[d]);
#pragma unroll
      for (int d = 0; d < 16; ++d) {
        float a = acc1[d];
#pragma unroll
        for (int r = 0; r < 9; ++r)
          a = fmaf(w1[(d * INC + cc) * 9 + r], v[r], a);
        acc1[d] = a;
      }
    }
  }
  const int y = y0 + ly, x = x0 + lx;
#pragma unroll
  for (int d = 0; d < 16; ++d) {
    const size_t o = (((size_t)b * HID + d) * HH + y) * WW + x;
    h0[o] = acc0[d] + b0[d];
    h1[o] = acc1[d] + b1[d];
  }
}

// ---------------------------------------------------------------------------
// Kernel B1: per-pixel attention. o1/o3 kept as PACKED bf16 (72 regs) so the
// peak live set (~200) fits without scratch spills. launch_bounds(64,1).
// ---------------------------------------------------------------------------
template <int SHIFT, int BRANCH>
__global__ __launch_bounds__(64, 1) void kernelB1(
    const float* __restrict__ h,  const float* __restrict__ w1,
    const float* __restrict__ w2, const float* __restrict__ w3,
    const float* __restrict__ scale, ushort_t* __restrict__ cat) {
  const int pix = blockIdx.x * 64 + threadIdx.x;
  const int b = pix / PIX; const int rem = pix - b * PIX;
  const int y = rem / WW;  const int x = rem - y * WW;
  const float sc = scale[BRANCH];

  constexpr int DY[9] = {-1, -1, -1, 0, 1, 1, 1, 0, 0};
  constexpr int DX[9] = {-1, 0, 1, 1, 1, 0, -1, -1, 0};

  const float* __restrict__ hb = h + (size_t)b * HID * PIX;

  auto loadX = [&](int g, float* xv) {
    if (g == 8) {
#pragma unroll
      for (int c = 0; c < 16; ++c) xv[c] = hb[c * PIX + y * WW + x];
    } else {
      const int yy = y + DY[g] * SHIFT, xx = x + DX[g] * SHIFT;
      if (yy >= 0 && yy < HH && xx >= 0 && xx < WW) {
#pragma unroll
        for (int c = 0; c < 16; ++c) xv[c] = -hb[c * PIX + yy * WW + xx];
      } else {
#pragma unroll
        for (int c = 0; c < 16; ++c) xv[c] = 0.f;
      }
    }
  };

  unsigned op[72];   // packed bf16 pairs: first o1, later reused for o3

  // ---- Phase A: o1 (packed) ----
#pragma unroll
  for (int q = 0; q < 9; ++q) {
    float xq[16];
    loadX(q, xq);
#pragma unroll
    for (int dd = 0; dd < 8; ++dd) {
      const float* wr0 = w1 + (q * 16 + 2 * dd) * 16;
      const float* wr1 = wr0 + 16;
      float a0 = 0.f, a1 = 0.f, c0 = 0.f, c1 = 0.f;
#pragma unroll
      for (int c = 0; c < 16; c += 2) {
        a0 = fmaf(wr0[c],     xq[c],     a0);
        a1 = fmaf(wr0[c + 1], xq[c + 1], a1);
        c0 = fmaf(wr1[c],     xq[c],     c0);
        c1 = fmaf(wr1[c + 1], xq[c + 1], c1);
      }
      op[q * 8 + dd] = pack2(a0 + a1, c0 + c1);
    }
  }

  // ---- Phase B: logits[p][q] ----
  float lg[81];
#pragma unroll
  for (int p = 0; p < 9; ++p) {
    float xp[16];
    loadX(p, xp);
    float o2p[16];
#pragma unroll
    for (int d = 0; d < 16; ++d) {
      const float* wr = w2 + (p * 16 + d) * 16;
      float a0 = 0.f, a1 = 0.f;
#pragma unroll
      for (int c = 0; c < 16; c += 2) {
        a0 = fmaf(wr[c],     xp[c],     a0);
        a1 = fmaf(wr[c + 1], xp[c + 1], a1);
      }
      o2p[d] = a0 + a1;
    }
#pragma unroll
    for (int q = 0; q < 9; ++q) {
      float s0 = 0.f, s1 = 0.f;
#pragma unroll
      for (int dd = 0; dd < 8; ++dd) {
        const unsigned u = op[q * 8 + dd];
        const float e0 = __uint_as_float(u << 16);
        const float e1 = __uint_as_float(u & 0xffff0000u);
        s0 = fmaf(o2p[2 * dd],     e0, s0);
        s1 = fmaf(o2p[2 * dd + 1], e1, s1);
      }
      lg[p * 9 + q] = s0 + s1;
    }
  }

  // ---- softmax over q (scale first; sc may be negative) ----
#pragma unroll
  for (int p = 0; p < 9; ++p) {
    float e[9]; float m = -1e30f;
#pragma unroll
    for (int q = 0; q < 9; ++q) { e[q] = sc * lg[p * 9 + q]; m = fmaxf(m, e[q]); }
    float s = 0.f;
#pragma unroll
    for (int q = 0; q < 9; ++q) { e[q] = __expf(e[q] - m); s += e[q]; }
    const float inv = 1.0f / s;
#pragma unroll
    for (int q = 0; q < 9; ++q) lg[p * 9 + q] = e[q] * inv;
  }

  // ---- Phase C: o3 (packed, overwrites op) ----
#pragma unroll
  for (int q = 0; q < 9; ++q) {
    float xq[16];
    loadX(q, xq);
#pragma unroll
    for (int dd = 0; dd < 8; ++dd) {
      const float* wr0 = w3 + (q * 16 + 2 * dd) * 16;
      const float* wr1 = wr0 + 16;
      float a0 = 0.f, a1 = 0.f, c0 = 0.f, c1 = 0.f;
#pragma unroll
      for (int c = 0; c < 16; c += 2) {
        a0 = fmaf(wr0[c],     xq[c],     a0);
        a1 = fmaf(wr0[c + 1], xq[c + 1], a1);
        c0 = fmaf(wr1[c],     xq[c],     c0);
        c1 = fmaf(wr1[c + 1], xq[c + 1], c1);
      }
      op[q * 8 + dd] = pack2(a0 + a1, c0 + c1);
    }
  }

  // ---- Phase D: ov[p] = sum_q attn[p][q] * o3[q]; store bf16 cat row ----
  ushort_t* __restrict__ crow = cat + (size_t)pix * CATK;
#pragma unroll
  for (int p = 0; p < 9; ++p) {
    float ov[16];
#pragma unroll
    for (int i = 0; i < 16; ++i) ov[i] = 0.f;
#pragma unroll
    for (int q = 0; q < 9; ++q) {
      const float a = lg[p * 9 + q];
#pragma unroll
      for (int dd = 0; dd < 8; ++dd) {
        const unsigned u = op[q * 8 + dd];
        const float e0 = __uint_as_float(u << 16);
        const float e1 = __uint_as_float(u & 0xffff0000u);
        ov[2 * dd]     = fmaf(a, e0, ov[2 * dd]);
        ov[2 * dd + 1] = fmaf(a, e1, ov[2 * dd + 1]);
      }
    }
    uint4 w;
    w.x = pack2(ov[0],  ov[1]);  w.y = pack2(ov[2],  ov[3]);
    w.z = pack2(ov[4],  ov[5]);  w.w = pack2(ov[6],  ov[7]);
    uint4 w2v;
    w2v.x = pack2(ov[8],  ov[9]);  w2v.y = pack2(ov[10], ov[11]);
    w2v.z = pack2(ov[12], ov[13]); w2v.w = pack2(ov[14], ov[15]);
    *(uint4*)(crow + p * 16) = w;
    *(uint4*)(crow + p * 16 + 8) = w2v;
  }
  *(uint4*)(crow + 144) = make_uint4(0, 0, 0, 0);
  *(uint4*)(crow + 152) = make_uint4(0, 0, 0, 0);
}

// ---------------------------------------------------------------------------
// Kernel B2 split (round-2) and fused variants.
// ---------------------------------------------------------------------------
template <int BRANCH, bool ACCUM>
__global__ __launch_bounds__(256) void kernelB2(
    const ushort_t* __restrict__ cat, const ushort_t* __restrict__ wb,
    const float* __restrict__ out_b, float* __restrict__ out) {
  const int wave = threadIdx.x >> 6;
  const int lane = threadIdx.x & 63;
  const int tile = blockIdx.x * 4 + wave;
  const int bpix0 = tile * 16;
  const int n = lane & 15, quad = lane >> 4;

  const bf16x8* __restrict__ bp =
      (const bf16x8*)(cat + (size_t)(bpix0 + n) * CATK + quad * 8);
  const ushort_t* __restrict__ wrow0 =
      wb + ((size_t)BRANCH * OUTC + n) * CATK + quad * 8;

  f32x4 acc[8];
#pragma unroll
  for (int mt = 0; mt < 8; ++mt) acc[mt] = (f32x4){0.f, 0.f, 0.f, 0.f};

#pragma unroll
  for (int kc = 0; kc < 5; ++kc) {
    const bf16x8 bfrag = bp[kc * 4];
#pragma unroll
    for (int mt = 0; mt < 8; ++mt) {
      const bf16x8 afrag =
          *(const bf16x8*)(wrow0 + (size_t)mt * 16 * CATK + kc * 32);
      acc[mt] = __builtin_amdgcn_mfma_f32_16x16x32_bf16(afrag, bfrag, acc[mt], 0, 0, 0);
    }
  }

  const int b = bpix0 / PIX;
  const int pin = bpix0 - b * PIX + n;
#pragma unroll
  for (int mt = 0; mt < 8; ++mt) {
#pragma unroll
    for (int i = 0; i < 4; ++i) {
      const int o = mt * 16 + quad * 4 + i;
      const size_t addr = ((size_t)(b * OUTC + o)) * PIX + pin;
      float r = acc[mt][i];
      if (ACCUM) r += out[addr]; else r += out_b[o];
      out[addr] = r;
    }
  }
}

__global__ __launch_bounds__(256) void kernelB2fused(
    const ushort_t* __restrict__ cat0, const ushort_t* __restrict__ cat1,
    const ushort_t* __restrict__ wb, const float* __restrict__ out_b,
    float* __restrict__ out) {
  const int wave = threadIdx.x >> 6;
  const int lane = threadIdx.x & 63;
  const int tile = blockIdx.x * 4 + wave;
  const int bpix0 = tile * 16;
  const int n = lane & 15, quad = lane >> 4;

  f32x4 acc[8];
#pragma unroll
  for (int mt = 0; mt < 8; ++mt) acc[mt] = (f32x4){0.f, 0.f, 0.f, 0.f};

#pragma unroll
  for (int br = 0; br < 2; ++br) {
    const ushort_t* cp = br ? cat1 : cat0;
    const bf16x8* __restrict__ bp =
        (const bf16x8*)(cp + (size_t)(bpix0 + n) * CATK + quad * 8);
    const ushort_t* __restrict__ wrow0 =
        wb + ((size_t)br * OUTC + n) * CATK + quad * 8;
#pragma unroll
    for (int kc = 0; kc < 5; ++kc) {
      const bf16x8 bfrag = bp[kc * 4];
#pragma unroll
      for (int mt = 0; mt < 8; ++mt) {
        const bf16x8 afrag =
            *(const bf16x8*)(wrow0 + (size_t)mt * 16 * CATK + kc * 32);
        acc[mt] = __builtin_amdgcn_mfma_f32_16x16x32_bf16(afrag, bfrag, acc[mt], 0, 0, 0);
      }
    }
  }

  const int b = bpix0 / PIX;
  const int pin = bpix0 - b * PIX + n;
#pragma unroll
  for (int mt = 0; mt < 8; ++mt) {
#pragma unroll
    for (int i = 0; i < 4; ++i) {
      const int o = mt * 16 + quad * 4 + i;
      const size_t addr = ((size_t)(b * OUTC + o)) * PIX + pin;
      out[addr] = acc[mt][i] + out_b[o];
    }
  }
}

// ---------------------------------------------------------------------------
extern "C" void kernel_launch(void* const* d_in, const int* in_sizes, int n_in,
                              void* d_out, int out_size, void* d_ws, size_t ws_size,
                              hipStream_t stream) {
  const float* cen   = (const float*)d_in[0];
  const float* in_w0 = (const float*)d_in[1];
  const float* in_b0 = (const float*)d_in[2];
  const float* in_w1 = (const float*)d_in[3];
  const float* in_b1 = (const float*)d_in[4];
  const float* w1_0  = (const float*)d_in[5];
  const float* w2_0  = (const float*)d_in[6];
  const float* w3_0  = (const float*)d_in[7];
  const float* w1_1  = (const float*)d_in[8];
  const float* w2_1  = (const float*)d_in[9];
  const float* w3_1  = (const float*)d_in[10];
  const float* scale = (const float*)d_in[11];
  const float* out_w = (const float*)d_in[12];
  const float* out_b = (const float*)d_in[13];
  float* out = (float*)d_out;

  // ---- ws layout ----
  const size_t H_ELEMS = (size_t)BATCH * HID * PIX;        // 2359296 floats
  const size_t PLANE_E = (size_t)BPIX * 256;               // cen_t plane, ushorts
  const size_t CAT_E   = (size_t)BPIX * CATK;              // cat, ushorts

  float* h0 = (float*)d_ws;
  float* h1 = h0 + H_ELEMS;
  ushort_t* wsm = (ushort_t*)(h1 + H_ELEMS);
  ushort_t* wA0hi = wsm;                 // 4096
  ushort_t* wA0lo = wsm + 4096;          // 4096
  ushort_t* wA1hi = wsm + 8192;          // 36864
  ushort_t* wA1lo = wsm + 45056;         // 36864
  ushort_t* wb    = wsm + 81920;         // 40960
  ushort_t* big   = wsm + 122880;

  const size_t base_bytes = 2 * H_ELEMS * 4 + 122880 * 2;
  const size_t fast_need       = base_bytes + 2 * PLANE_E * 2;   // ~170 MB
  const size_t slow_fused_need = base_bytes + 2 * CAT_E * 2;     // ~113 MB
  const bool fast  = ws_size >= fast_need;
  const bool fused = fast || ws_size >= slow_fused_need;

  ushort_t* cat0 = big;                         // fast: aliases cen_t (safe: stream-ordered)
  ushort_t* cat1 = fused ? (big + CAT_E) : big;

  // ---- weight preps ----
  hipLaunchKernelGGL(wprepB, dim3((2 * OUTC * CATK + 255) / 256), dim3(256), 0,
                     stream, out_w, wb);

  // ---- input convs ----
  if (fast) {
    ushort_t* th = big;
    ushort_t* tl = big + PLANE_E;
    hipLaunchKernelGGL(wprepA, dim3(144), dim3(256), 0, stream,
                       in_w0, in_w1, wA0hi, wA0lo, wA1hi, wA1lo);
    hipLaunchKernelGGL(kernelP, dim3(WW / 16, HH, BATCH), dim3(256), 0, stream,
                       cen, th, tl);
    hipLaunchKernelGGL(kernelA_mfma, dim3(3, HH, BATCH), dim3(256), 0, stream,
                       th, tl, wA0hi, wA0lo, wA1hi, wA1lo, in_b0, in_b1, h0, h1);
  } else {
    hipLaunchKernelGGL(kernelA_f32, dim3(WW / 16, HH / 16, BATCH), dim3(16, 16), 0,
                       stream, cen, in_w0, in_b0, in_w1, in_b1, h0, h1);
  }

  const int nb1 = BPIX / 64;        // 2304
  const int nb2 = (BPIX / 16) / 4;  // 2304

  if (fused) {
    hipLaunchKernelGGL((kernelB1<1, 0>), dim3(nb1), dim3(64), 0, stream,
                       h0, w1_0, w2_0, w3_0, scale, cat0);
    hipLaunchKernelGGL((kernelB1<5, 1>), dim3(nb1), dim3(64), 0, stream,
                       h1, w1_1, w2_1, w3_1, scale, cat1);
    hipLaunchKernelGGL(kernelB2fused, dim3(nb2), dim3(256), 0, stream,
                       cat0, cat1, wb, out_b, out);
  } else {
    hipLaunchKernelGGL((kernelB1<1, 0>), dim3(nb1), dim3(64), 0, stream,
                       h0, w1_0, w2_0, w3_0, scale, cat0);
    hipLaunchKernelGGL((kernelB2<0, false>), dim3(nb2), dim3(256), 0, stream,
                       cat0, wb, out_b, out);
    hipLaunchKernelGGL((kernelB1<5, 1>), dim3(nb1), dim3(64), 0, stream,
                       h1, w1_1, w2_1, w3_1, scale, cat1);
    hipLaunchKernelGGL((kernelB2<1, true>), dim3(nb2), dim3(256), 0, stream,
                       cat1, wb, out_b, out);
  }
}

// Round 4
// 660.269 us; speedup vs baseline: 4.9350x; 4.0426x over previous
//
#include <hip/hip_runtime.h>
#include <hip/hip_bf16.h>
#include <cstddef>
#include <cstdint>

// Problem constants
#define BATCH 4
#define INC   256
#define HID   16
#define NL    9
#define HH    192
#define WW    192
#define PIX   (HH*WW)          // 36864
#define BPIX  (BATCH*PIX)      // 147456
#define OUTC  128
#define CATC  (NL*HID*2)       // 288
#define CATK  160              // per-branch K padded 144 -> 160 (5 x 32)

typedef __attribute__((ext_vector_type(8))) short bf16x8;
typedef __attribute__((ext_vector_type(4))) float f32x4;
typedef unsigned short ushort_t;

__device__ inline unsigned short f2bf(float f) {
  unsigned int u = __float_as_uint(f);
  u += 0x7FFF + ((u >> 16) & 1);   // round-to-nearest-even
  return (unsigned short)(u >> 16);
}
__device__ inline float bf2f(unsigned short s) {
  return __uint_as_float(((unsigned)s) << 16);
}
__device__ inline unsigned pack2(float a, float b) {
  return (unsigned)f2bf(a) | ((unsigned)f2bf(b) << 16);
}
__device__ inline bf16x8 cvt8(float4 a, float4 b) {
  union { bf16x8 v; unsigned u[4]; } r;
  r.u[0] = pack2(a.x, a.y); r.u[1] = pack2(a.z, a.w);
  r.u[2] = pack2(b.x, b.y); r.u[3] = pack2(b.z, b.w);
  return r.v;
}

// ---------------------------------------------------------------------------
// kernelP: cen (NCHW fp32) -> cen_t hi/lo (NHWC bf16 planes)
// ---------------------------------------------------------------------------
__global__ __launch_bounds__(256) void kernelP(const float* __restrict__ cen,
                                               ushort_t* __restrict__ th,
                                               ushort_t* __restrict__ tl) {
  __shared__ float t[256][17];
  const int b = blockIdx.z, y = blockIdx.y, x0 = blockIdx.x * 16;
  const int tid = threadIdx.x;
#pragma unroll
  for (int k = 0; k < 16; ++k) {
    int i = tid + k * 256; int c = i >> 4, xl = i & 15;
    t[c][xl] = cen[((size_t)(b * 256 + c)) * PIX + (size_t)y * WW + x0 + xl];
  }
  __syncthreads();
  const size_t obase = (((size_t)b * HH + y) * WW + x0) * 256;
#pragma unroll
  for (int xl = 0; xl < 16; ++xl) {
    float v = t[tid][xl];
    unsigned short hi = f2bf(v);
    th[obase + (size_t)xl * 256 + tid] = hi;
    tl[obase + (size_t)xl * 256 + tid] = f2bf(v - bf2f(hi));
  }
}

// ---------------------------------------------------------------------------
// wprepA: MFMA-frag-ready bf16 hi/lo weights for the two input convs.
// ---------------------------------------------------------------------------
__global__ __launch_bounds__(256) void wprepA(
    const float* __restrict__ w0, const float* __restrict__ w1,
    ushort_t* __restrict__ wA0hi, ushort_t* __restrict__ wA0lo,
    ushort_t* __restrict__ wA1hi, ushort_t* __restrict__ wA1lo) {
  int idx = blockIdx.x * 256 + threadIdx.x;
  if (idx < 36864) {
    int j = idx & 7, l = (idx >> 3) & 63, kc = (idx >> 9) & 7, s = idx >> 12;
    int d = l & 15, c = kc * 32 + (l >> 4) * 8 + j;
    float v = w1[(size_t)(d * 256 + c) * 9 + s];
    unsigned short hi = f2bf(v);
    wA1hi[idx] = hi; wA1lo[idx] = f2bf(v - bf2f(hi));
  }
  if (idx < 4096) {
    int j = idx & 7, l = (idx >> 3) & 63, kc = idx >> 9;
    int d = l & 15, c = kc * 32 + (l >> 4) * 8 + j;
    float v = w0[d * 256 + c];
    unsigned short hi = f2bf(v);
    wA0hi[idx] = hi; wA0lo[idx] = f2bf(v - bf2f(hi));
  }
}

// ---------------------------------------------------------------------------
// wprepB: out_w (fp32, [128][288]) -> wb (bf16, [branch][128][CATK]), K-padded
// ---------------------------------------------------------------------------
__global__ __launch_bounds__(256) void wprepB(const float* __restrict__ out_w,
                                              ushort_t* __restrict__ wb) {
  int idx = blockIdx.x * 256 + threadIdx.x;
  if (idx >= 2 * OUTC * CATK) return;
  int k = idx % CATK; int rest = idx / CATK;
  int o = rest % OUTC; int br = rest / OUTC;
  float v = (k < 144) ? out_w[o * CATC + br * 144 + k] : 0.f;
  wb[idx] = f2bf(v);
}

// ---------------------------------------------------------------------------
// wprepM: w1/w2/w3 (both branches) -> A-frag bf16 layout for kernelB1m.
// wm[br][mat][g][lane*8+j]: m=lane&15 -> d, k=(lane>>4)*8+j -> c (c>=16: 0).
// Sign folded: groups 0..7 use -w (x = -h_shift), group 8 uses +w.
// ---------------------------------------------------------------------------
__global__ __launch_bounds__(256) void wprepM(
    const float* __restrict__ w1_0, const float* __restrict__ w2_0,
    const float* __restrict__ w3_0, const float* __restrict__ w1_1,
    const float* __restrict__ w2_1, const float* __restrict__ w3_1,
    ushort_t* __restrict__ wm) {
  int idx = blockIdx.x * 256 + threadIdx.x;
  if (idx >= 2 * 27 * 512) return;
  int j = idx & 7;
  int lane = (idx >> 3) & 63;
  int blk = idx >> 9;               // br*27 + mat*9 + g
  int g = blk % 9, mat = (blk / 9) % 3, br = blk / 27;
  int d = lane & 15, k = (lane >> 4) * 8 + j;
  float v = 0.f;
  if (k < 16) {
    const float* w;
    if (br == 0) w = (mat == 0) ? w1_0 : (mat == 1) ? w2_0 : w3_0;
    else         w = (mat == 0) ? w1_1 : (mat == 1) ? w2_1 : w3_1;
    v = w[(g * 16 + d) * 16 + k];
    if (g < 8) v = -v;
  }
  wm[idx] = f2bf(v);
}

// ---------------------------------------------------------------------------
// kernelA_mfma: acc1 += 3x3 conv (9 taps), acc0 += 1x1 (center), hi/lo bf16.
// Output h layout: NHWC [b][pix][16] fp32.
// ---------------------------------------------------------------------------
template <bool SAFE>
__device__ inline void a_tile(const ushort_t* __restrict__ th,
                              const ushort_t* __restrict__ tl,
                              const ushort_t* __restrict__ wA0hi,
                              const ushort_t* __restrict__ wA0lo,
                              const ushort_t* __restrict__ wA1hi,
                              const ushort_t* __restrict__ wA1lo,
                              int b, int y, int px, f32x4& acc0, f32x4& acc1) {
  const int lane = threadIdx.x & 63;
  const int quad = lane >> 4;
  const bf16x8 bz = {0, 0, 0, 0, 0, 0, 0, 0};
#pragma unroll
  for (int sy = 0; sy < 3; ++sy) {
    const int yy = y + sy - 1;
    const bool yok = SAFE || ((unsigned)yy < (unsigned)HH);
#pragma unroll
    for (int sx = 0; sx < 3; ++sx) {
      const int xx = px + sx - 1;
      const bool ok = SAFE || (yok && ((unsigned)xx < (unsigned)WW));
      const int cy = SAFE ? yy : (ok ? yy : 0);
      const int cx = SAFE ? xx : (ok ? xx : 0);
      const size_t base = (((size_t)(b * HH + cy) * WW) + cx) * 256 + quad * 8;
      const int s = sy * 3 + sx;
      const ushort_t* wh = wA1hi + s * 4096 + lane * 8;
      const ushort_t* wl = wA1lo + s * 4096 + lane * 8;
#pragma unroll
      for (int kc = 0; kc < 8; ++kc) {
        bf16x8 bhi = *(const bf16x8*)(th + base + kc * 32);
        bf16x8 blo = *(const bf16x8*)(tl + base + kc * 32);
        if (!SAFE && !ok) { bhi = bz; blo = bz; }
        bf16x8 ahi = *(const bf16x8*)(wh + kc * 512);
        bf16x8 alo = *(const bf16x8*)(wl + kc * 512);
        acc1 = __builtin_amdgcn_mfma_f32_16x16x32_bf16(ahi, bhi, acc1, 0, 0, 0);
        acc1 = __builtin_amdgcn_mfma_f32_16x16x32_bf16(ahi, blo, acc1, 0, 0, 0);
        acc1 = __builtin_amdgcn_mfma_f32_16x16x32_bf16(alo, bhi, acc1, 0, 0, 0);
        if (s == 4) {
          bf16x8 a0h = *(const bf16x8*)(wA0hi + kc * 512 + lane * 8);
          bf16x8 a0l = *(const bf16x8*)(wA0lo + kc * 512 + lane * 8);
          acc0 = __builtin_amdgcn_mfma_f32_16x16x32_bf16(a0h, bhi, acc0, 0, 0, 0);
          acc0 = __builtin_amdgcn_mfma_f32_16x16x32_bf16(a0h, blo, acc0, 0, 0, 0);
          acc0 = __builtin_amdgcn_mfma_f32_16x16x32_bf16(a0l, bhi, acc0, 0, 0, 0);
        }
      }
    }
  }
}

__global__ __launch_bounds__(256) void kernelA_mfma(
    const ushort_t* __restrict__ th, const ushort_t* __restrict__ tl,
    const ushort_t* __restrict__ wA0hi, const ushort_t* __restrict__ wA0lo,
    const ushort_t* __restrict__ wA1hi, const ushort_t* __restrict__ wA1lo,
    const float* __restrict__ b0, const float* __restrict__ b1,
    float* __restrict__ h0, float* __restrict__ h1) {
  const int lane = threadIdx.x & 63, wave = threadIdx.x >> 6;
  const int n = lane & 15, quad = lane >> 4;
  const int y = blockIdx.y, b = blockIdx.z;
  const int wpx0 = blockIdx.x * 64 + wave * 16;
  const int px = wpx0 + n;
  f32x4 acc0 = {0.f, 0.f, 0.f, 0.f}, acc1 = {0.f, 0.f, 0.f, 0.f};

  const bool safe = (y >= 1) && (y <= HH - 2) && (wpx0 >= 1) && (wpx0 + 16 <= WW - 1);
  if (safe)
    a_tile<true>(th, tl, wA0hi, wA0lo, wA1hi, wA1lo, b, y, px, acc0, acc1);
  else
    a_tile<false>(th, tl, wA0hi, wA0lo, wA1hi, wA1lo, b, y, px, acc0, acc1);

  // NHWC store: lane holds d = quad*4 + i for pixel px.
  const size_t pb = ((size_t)b * PIX + (size_t)y * WW + px) * 16 + quad * 4;
  float4 r0, r1;
  r0.x = acc0[0] + b0[quad * 4 + 0]; r0.y = acc0[1] + b0[quad * 4 + 1];
  r0.z = acc0[2] + b0[quad * 4 + 2]; r0.w = acc0[3] + b0[quad * 4 + 3];
  r1.x = acc1[0] + b1[quad * 4 + 0]; r1.y = acc1[1] + b1[quad * 4 + 1];
  r1.z = acc1[2] + b1[quad * 4 + 2]; r1.w = acc1[3] + b1[quad * 4 + 3];
  *(float4*)(h0 + pb) = r0;
  *(float4*)(h1 + pb) = r1;
}

// ---------------------------------------------------------------------------
// kernelA_f32: fallback when ws too small for cen_t planes. NHWC output.
// ---------------------------------------------------------------------------
__global__ __launch_bounds__(256) void kernelA_f32(
    const float* __restrict__ cen, const float* __restrict__ w0,
    const float* __restrict__ b0,  const float* __restrict__ w1,
    const float* __restrict__ b1,  float* __restrict__ h0,
    float* __restrict__ h1) {
  __shared__ float lds[16 * 18 * 18];
  const int lx = threadIdx.x, ly = threadIdx.y;
  const int tid = ly * 16 + lx;
  const int x0 = blockIdx.x * 16, y0 = blockIdx.y * 16, b = blockIdx.z;

  float acc0[16], acc1[16];
#pragma unroll
  for (int d = 0; d < 16; ++d) { acc0[d] = 0.f; acc1[d] = 0.f; }

  for (int cb = 0; cb < INC; cb += 16) {
    __syncthreads();
    for (int i = tid; i < 16 * 18 * 18; i += 256) {
      int c = i / 324; int rem = i - c * 324;
      int yy = rem / 18; int xx = rem - yy * 18;
      int gy = y0 + yy - 1, gx = x0 + xx - 1;
      float v = 0.f;
      if (gy >= 0 && gy < HH && gx >= 0 && gx < WW)
        v = cen[(((size_t)b * INC + cb + c) * HH + gy) * WW + gx];
      lds[i] = v;
    }
    __syncthreads();
    for (int c = 0; c < 16; ++c) {
      float v[9];
#pragma unroll
      for (int r = 0; r < 9; ++r) {
        const int dy = r / 3, dx = r - (r / 3) * 3;
        v[r] = lds[(c * 18 + ly + dy) * 18 + lx + dx];
      }
      const int cc = cb + c;
#pragma unroll
      for (int d = 0; d < 16; ++d)
        acc0[d] = fmaf(w0[d * INC + cc], v[4], acc0[d]);
#pragma unroll
      for (int d = 0; d < 16; ++d) {
        float a = acc1[d];
#pragma unroll
        for (int r = 0; r < 9; ++r)
          a = fmaf(w1[(d * INC + cc) * 9 + r], v[r], a);
        acc1[d] = a;
      }
    }
  }
  const int y = y0 + ly, x = x0 + lx;
  const size_t base = ((size_t)b * PIX + (size_t)y * WW + x) * 16;
#pragma unroll
  for (int k = 0; k < 4; ++k) {
    float4 r0, r1;
    r0.x = acc0[4 * k + 0] + b0[4 * k + 0]; r0.y = acc0[4 * k + 1] + b0[4 * k + 1];
    r0.z = acc0[4 * k + 2] + b0[4 * k + 2]; r0.w = acc0[4 * k + 3] + b0[4 * k + 3];
    r1.x = acc1[4 * k + 0] + b1[4 * k + 0]; r1.y = acc1[4 * k + 1] + b1[4 * k + 1];
    r1.z = acc1[4 * k + 2] + b1[4 * k + 2]; r1.w = acc1[4 * k + 3] + b1[4 * k + 3];
    *(float4*)(h0 + base + 4 * k) = r0;
    *(float4*)(h1 + base + 4 * k) = r1;
  }
}

// ---------------------------------------------------------------------------
// kernelB1m: wave-cooperative attention. Wave = 16 pixels of one row.
// o1/o2/o3 via 16x16x32 bf16 MFMA (K zero-padded); logits via in-lane dot
// + shfl_xor quad reduction; softmax + PV on VALU. ~160 VGPR, no spills.
// ---------------------------------------------------------------------------
template <int SHIFT, int BRANCH>
__global__ __launch_bounds__(256) void kernelB1m(
    const float* __restrict__ h,      // [b][pix][16] fp32
    const ushort_t* __restrict__ wm,  // [br][3][9][512] bf16 A-frags
    const float* __restrict__ scale, ushort_t* __restrict__ cat) {
  const int lane = threadIdx.x & 63;
  const int gw = blockIdx.x * 4 + (threadIdx.x >> 6);
  const int bpix0 = gw * 16;
  const int b = bpix0 / PIX;
  const int rem = bpix0 - b * PIX;
  const int y = rem / WW, x0 = rem - y * WW;
  const int n = lane & 15, quad = lane >> 4;
  const float sc = scale[BRANCH];
  const float* __restrict__ hb = h + (size_t)b * PIX * 16;
  const ushort_t* __restrict__ wmb = wm + (size_t)BRANCH * 27 * 512;

  constexpr int DY[9] = {-1, -1, -1, 0, 1, 1, 1, 0, 0};
  constexpr int DX[9] = {-1, 0, 1, 1, 1, 0, -1, -1, 0};

  // B-frags: lane provides B[k = quad*8+j][pixel n]; k>=16 must be zero.
  bf16x8 xf[9];
#pragma unroll
  for (int g = 0; g < 9; ++g) {
    bf16x8 v = {0, 0, 0, 0, 0, 0, 0, 0};
    const int yy = y + DY[g] * SHIFT;
    const int xx = x0 + n + DX[g] * SHIFT;
    if (quad < 2 && (unsigned)yy < (unsigned)HH && (unsigned)xx < (unsigned)WW) {
      const float4* p = (const float4*)(hb + ((size_t)yy * WW + xx) * 16 + quad * 8);
      v = cvt8(p[0], p[1]);
    }
    xf[g] = v;
  }

  const f32x4 zero4 = {0.f, 0.f, 0.f, 0.f};
  f32x4 o1[9], o3[9];
#pragma unroll
  for (int g = 0; g < 9; ++g) {
    const bf16x8 a1 = *(const bf16x8*)(wmb + (0 * 9 + g) * 512 + lane * 8);
    o1[g] = __builtin_amdgcn_mfma_f32_16x16x32_bf16(a1, xf[g], zero4, 0, 0, 0);
  }
#pragma unroll
  for (int g = 0; g < 9; ++g) {
    const bf16x8 a3 = *(const bf16x8*)(wmb + (2 * 9 + g) * 512 + lane * 8);
    o3[g] = __builtin_amdgcn_mfma_f32_16x16x32_bf16(a3, xf[g], zero4, 0, 0, 0);
  }

  ushort_t* __restrict__ crow = cat + (size_t)(bpix0 + n) * CATK;

#pragma unroll
  for (int p = 0; p < 9; ++p) {
    const bf16x8 a2 = *(const bf16x8*)(wmb + (1 * 9 + p) * 512 + lane * 8);
    const f32x4 o2p = __builtin_amdgcn_mfma_f32_16x16x32_bf16(a2, xf[p], zero4, 0, 0, 0);
    float e[9]; float m = -1e30f;
#pragma unroll
    for (int q = 0; q < 9; ++q) {
      float t = (o2p[0] * o1[q][0] + o2p[1] * o1[q][1]) +
                (o2p[2] * o1[q][2] + o2p[3] * o1[q][3]);
      t += __shfl_xor(t, 16);
      t += __shfl_xor(t, 32);
      e[q] = sc * t;
      m = fmaxf(m, e[q]);
    }
    float s = 0.f;
#pragma unroll
    for (int q = 0; q < 9; ++q) { e[q] = __expf(e[q] - m); s += e[q]; }
    const float inv = 1.0f / s;
    f32x4 ov = zero4;
#pragma unroll
    for (int q = 0; q < 9; ++q) {
      const float a = e[q] * inv;
      ov[0] = fmaf(a, o3[q][0], ov[0]);
      ov[1] = fmaf(a, o3[q][1], ov[1]);
      ov[2] = fmaf(a, o3[q][2], ov[2]);
      ov[3] = fmaf(a, o3[q][3], ov[3]);
    }
    uint2 w; w.x = pack2(ov[0], ov[1]); w.y = pack2(ov[2], ov[3]);
    *(uint2*)(crow + p * 16 + quad * 4) = w;
  }
  // zero K-pad [144,160): quads 0/1 write 8 ushorts each
  if (quad < 2)
    *(uint4*)(crow + 144 + quad * 8) = make_uint4(0, 0, 0, 0);
}

// ---------------------------------------------------------------------------
// Kernel B2 split and fused variants (final 1x1 conv as bf16 MFMA GEMM).
// ---------------------------------------------------------------------------
template <int BRANCH, bool ACCUM>
__global__ __launch_bounds__(256) void kernelB2(
    const ushort_t* __restrict__ cat, const ushort_t* __restrict__ wb,
    const float* __restrict__ out_b, float* __restrict__ out) {
  const int wave = threadIdx.x >> 6;
  const int lane = threadIdx.x & 63;
  const int tile = blockIdx.x * 4 + wave;
  const int bpix0 = tile * 16;
  const int n = lane & 15, quad = lane >> 4;

  const bf16x8* __restrict__ bp =
      (const bf16x8*)(cat + (size_t)(bpix0 + n) * CATK + quad * 8);
  const ushort_t* __restrict__ wrow0 =
      wb + ((size_t)BRANCH * OUTC + n) * CATK + quad * 8;

  f32x4 acc[8];
#pragma unroll
  for (int mt = 0; mt < 8; ++mt) acc[mt] = (f32x4){0.f, 0.f, 0.f, 0.f};

#pragma unroll
  for (int kc = 0; kc < 5; ++kc) {
    const bf16x8 bfrag = bp[kc * 4];
#pragma unroll
    for (int mt = 0; mt < 8; ++mt) {
      const bf16x8 afrag =
          *(const bf16x8*)(wrow0 + (size_t)mt * 16 * CATK + kc * 32);
      acc[mt] = __builtin_amdgcn_mfma_f32_16x16x32_bf16(afrag, bfrag, acc[mt], 0, 0, 0);
    }
  }

  const int b = bpix0 / PIX;
  const int pin = bpix0 - b * PIX + n;
#pragma unroll
  for (int mt = 0; mt < 8; ++mt) {
#pragma unroll
    for (int i = 0; i < 4; ++i) {
      const int o = mt * 16 + quad * 4 + i;
      const size_t addr = ((size_t)(b * OUTC + o)) * PIX + pin;
      float r = acc[mt][i];
      if (ACCUM) r += out[addr]; else r += out_b[o];
      out[addr] = r;
    }
  }
}

__global__ __launch_bounds__(256) void kernelB2fused(
    const ushort_t* __restrict__ cat0, const ushort_t* __restrict__ cat1,
    const ushort_t* __restrict__ wb, const float* __restrict__ out_b,
    float* __restrict__ out) {
  const int wave = threadIdx.x >> 6;
  const int lane = threadIdx.x & 63;
  const int tile = blockIdx.x * 4 + wave;
  const int bpix0 = tile * 16;
  const int n = lane & 15, quad = lane >> 4;

  f32x4 acc[8];
#pragma unroll
  for (int mt = 0; mt < 8; ++mt) acc[mt] = (f32x4){0.f, 0.f, 0.f, 0.f};

#pragma unroll
  for (int br = 0; br < 2; ++br) {
    const ushort_t* cp = br ? cat1 : cat0;
    const bf16x8* __restrict__ bp =
        (const bf16x8*)(cp + (size_t)(bpix0 + n) * CATK + quad * 8);
    const ushort_t* __restrict__ wrow0 =
        wb + ((size_t)br * OUTC + n) * CATK + quad * 8;
#pragma unroll
    for (int kc = 0; kc < 5; ++kc) {
      const bf16x8 bfrag = bp[kc * 4];
#pragma unroll
      for (int mt = 0; mt < 8; ++mt) {
        const bf16x8 afrag =
            *(const bf16x8*)(wrow0 + (size_t)mt * 16 * CATK + kc * 32);
        acc[mt] = __builtin_amdgcn_mfma_f32_16x16x32_bf16(afrag, bfrag, acc[mt], 0, 0, 0);
      }
    }
  }

  const int b = bpix0 / PIX;
  const int pin = bpix0 - b * PIX + n;
#pragma unroll
  for (int mt = 0; mt < 8; ++mt) {
#pragma unroll
    for (int i = 0; i < 4; ++i) {
      const int o = mt * 16 + quad * 4 + i;
      const size_t addr = ((size_t)(b * OUTC + o)) * PIX + pin;
      out[addr] = acc[mt][i] + out_b[o];
    }
  }
}

// ---------------------------------------------------------------------------
extern "C" void kernel_launch(void* const* d_in, const int* in_sizes, int n_in,
                              void* d_out, int out_size, void* d_ws, size_t ws_size,
                              hipStream_t stream) {
  const float* cen   = (const float*)d_in[0];
  const float* in_w0 = (const float*)d_in[1];
  const float* in_b0 = (const float*)d_in[2];
  const float* in_w1 = (const float*)d_in[3];
  const float* in_b1 = (const float*)d_in[4];
  const float* w1_0  = (const float*)d_in[5];
  const float* w2_0  = (const float*)d_in[6];
  const float* w3_0  = (const float*)d_in[7];
  const float* w1_1  = (const float*)d_in[8];
  const float* w2_1  = (const float*)d_in[9];
  const float* w3_1  = (const float*)d_in[10];
  const float* scale = (const float*)d_in[11];
  const float* out_w = (const float*)d_in[12];
  const float* out_b = (const float*)d_in[13];
  float* out = (float*)d_out;

  // ---- ws layout ----
  const size_t H_ELEMS = (size_t)BATCH * HID * PIX;        // 2359296 floats
  const size_t PLANE_E = (size_t)BPIX * 256;               // cen_t plane, ushorts
  const size_t CAT_E   = (size_t)BPIX * CATK;              // cat, ushorts

  float* h0 = (float*)d_ws;
  float* h1 = h0 + H_ELEMS;
  ushort_t* wsm = (ushort_t*)(h1 + H_ELEMS);
  ushort_t* wA0hi = wsm;                 // 4096
  ushort_t* wA0lo = wsm + 4096;          // 4096
  ushort_t* wA1hi = wsm + 8192;          // 36864
  ushort_t* wA1lo = wsm + 45056;         // 36864
  ushort_t* wb    = wsm + 81920;         // 40960
  ushort_t* wm    = wsm + 122880;        // 27648
  ushort_t* big   = wsm + 150528;

  const size_t base_bytes = 2 * H_ELEMS * 4 + 150528 * 2;
  const size_t fast_need       = base_bytes + 2 * PLANE_E * 2;   // ~170 MB
  const size_t slow_fused_need = base_bytes + 2 * CAT_E * 2;     // ~114 MB
  const bool fast  = ws_size >= fast_need;
  const bool fused = fast || ws_size >= slow_fused_need;

  ushort_t* cat0 = big;                         // fast: aliases cen_t (stream-ordered)
  ushort_t* cat1 = fused ? (big + CAT_E) : big;

  // ---- weight preps ----
  hipLaunchKernelGGL(wprepB, dim3((2 * OUTC * CATK + 255) / 256), dim3(256), 0,
                     stream, out_w, wb);
  hipLaunchKernelGGL(wprepM, dim3((2 * 27 * 512 + 255) / 256), dim3(256), 0,
                     stream, w1_0, w2_0, w3_0, w1_1, w2_1, w3_1, wm);

  // ---- input convs ----
  if (fast) {
    ushort_t* th = big;
    ushort_t* tl = big + PLANE_E;
    hipLaunchKernelGGL(wprepA, dim3(144), dim3(256), 0, stream,
                       in_w0, in_w1, wA0hi, wA0lo, wA1hi, wA1lo);
    hipLaunchKernelGGL(kernelP, dim3(WW / 16, HH, BATCH), dim3(256), 0, stream,
                       cen, th, tl);
    hipLaunchKernelGGL(kernelA_mfma, dim3(3, HH, BATCH), dim3(256), 0, stream,
                       th, tl, wA0hi, wA0lo, wA1hi, wA1lo, in_b0, in_b1, h0, h1);
  } else {
    hipLaunchKernelGGL(kernelA_f32, dim3(WW / 16, HH / 16, BATCH), dim3(16, 16), 0,
                       stream, cen, in_w0, in_b0, in_w1, in_b1, h0, h1);
  }

  const int nb1 = (BPIX / 16) / 4;  // 2304 blocks, 4 waves each
  const int nb2 = (BPIX / 16) / 4;  // 2304

  if (fused) {
    hipLaunchKernelGGL((kernelB1m<1, 0>), dim3(nb1), dim3(256), 0, stream,
                       h0, wm, scale, cat0);
    hipLaunchKernelGGL((kernelB1m<5, 1>), dim3(nb1), dim3(256), 0, stream,
                       h1, wm, scale, cat1);
    hipLaunchKernelGGL(kernelB2fused, dim3(nb2), dim3(256), 0, stream,
                       cat0, cat1, wb, out_b, out);
  } else {
    hipLaunchKernelGGL((kernelB1m<1, 0>), dim3(nb1), dim3(256), 0, stream,
                       h0, wm, scale, cat0);
    hipLaunchKernelGGL((kernelB2<0, false>), dim3(nb2), dim3(256), 0, stream,
                       cat0, wb, out_b, out);
    hipLaunchKernelGGL((kernelB1m<5, 1>), dim3(nb1), dim3(256), 0, stream,
                       h1, w1_1 ? wm : wm, scale, cat1);
    hipLaunchKernelGGL((kernelB2<1, true>), dim3(nb2), dim3(256), 0, stream,
                       cat1, wb, out_b, out);
  }
}